// Round 2
// baseline (91.714 us; speedup 1.0000x reference)
//
#include <hip/hip_runtime.h>
#include <hip/hip_bf16.h>

// GMM log-likelihood, N=65536, K=32, F=128.
// g-split design: wave wid owns g-tile gt=wid (32 rows of P^T). Each wave holds
// B (x) fragments for 4 n-tiles (128 rows) in registers; every A fragment read
// from LDS feeds 4 MFMAs. -mu@P is folded into the MFMA C-initializer.
// Per-comp cross-wave reduce of partial row-sums via red[128][4] in LDS.

#define NPTS 65536
#define KC 32
#define FD 128
#define SLABB 32768  // 4 gt * 8 s * 64 lanes * 16 B

typedef __attribute__((ext_vector_type(8))) short short8;
typedef __attribute__((ext_vector_type(8))) unsigned short ushort8;
typedef __attribute__((ext_vector_type(16))) float f32x16;

static __device__ __forceinline__ unsigned short f2bf(float f) {
  unsigned int u = __float_as_uint(f);
  u += 0x7FFFu + ((u >> 16) & 1u);  // RNE
  return (unsigned short)(u >> 16);
}

// --- prep 1: mp2 (permuted -mu@P projections) + ck2 ---
// mp2[((k*4+gt)*2+half)*16 + i] = sum_f means[k][f]*P[k][f][g],
//   g = gt*32 + 4*half + (i&3) + 8*(i>>2)   (matches 32x32 MFMA C-row layout)
__global__ void prep_mproj(const float* __restrict__ means, const float* __restrict__ P,
                           const float* __restrict__ w, float* __restrict__ mp2,
                           float* __restrict__ ck2) {
  int k = blockIdx.x, g = threadIdx.x;  // 32 x 128
  const float* Pk = P + k * FD * FD;
  float acc = 0.f;
  for (int f = 0; f < FD; ++f) acc = fmaf(means[k * FD + f], Pk[f * FD + g], acc);
  int gt = g >> 5, r = g & 31;
  int half = (r >> 2) & 1;
  int i = (r & 3) | ((r >> 3) << 2);
  mp2[((k * 4 + gt) * 2 + half) * 16 + i] = acc;
  __shared__ float red[FD];
  red[g] = logf(Pk[g * FD + g]);
  __syncthreads();
  for (int off = 64; off; off >>= 1) {
    if (g < off) red[g] += red[g + off];
    __syncthreads();
  }
  if (g == 0) ck2[k] = logf(w[k]) + red[0] - 0.5f * (float)FD * 1.8378770664093453f;
}

// --- prep 2: frag-major bf16 A image. chunk id -> (k,gt,s,lane).
// lane l supplies row g=gt*32+(l&31), elements f = 16s + 8*(l>>5) + j.
__global__ void prep_A(const float* __restrict__ P, unsigned char* __restrict__ Aimg) {
  int id = blockIdx.x * 256 + threadIdx.x;  // 0..65535
  int l = id & 63;
  int s = (id >> 6) & 7;
  int gt = (id >> 9) & 3;
  int k = id >> 11;
  int g = gt * 32 + (l & 31);
  int f0 = 16 * s + 8 * (l >> 5);
  ushort8 v;
#pragma unroll
  for (int j = 0; j < 8; ++j) v[j] = f2bf(P[k * 16384 + (f0 + j) * 128 + g]);
  *(ushort8*)(Aimg + (size_t)id * 16) = v;
}

// --- main ---
template <int RB, int WB, bool LAST>
__device__ __forceinline__ void comp_body(int k, const unsigned char* __restrict__ Aimg,
                                          const float* __restrict__ mp2,
                                          unsigned char* abuf, float (*red)[4],
                                          const float* ck, int tid, int wid, int lane,
                                          int half, int ln, const short8 (&xf)[4][8],
                                          float& m, float& ssum) {
  // mp loads FIRST so the later vmcnt(8) keeps only the 8 stage loads in flight
  const float4* mpp = (const float4*)(mp2 + ((size_t)(k * 4 + wid) * 2 + half) * 16);
  float4 m0 = mpp[0], m1 = mpp[1], m2 = mpp[2], m3 = mpp[3];
  if (!LAST) {  // prefetch next comp's slab slice (own wave's quarter only)
    const unsigned char* gs = Aimg + (size_t)(k + 1) * SLABB + wid * 8192 + lane * 16;
    unsigned char* ls = abuf + WB + wid * 8192;
#pragma unroll
    for (int i = 0; i < 8; ++i)
      __builtin_amdgcn_global_load_lds(
          (const __attribute__((address_space(1))) void*)(gs + i * 1024),
          (__attribute__((address_space(3))) void*)(ls + i * 1024), 16, 0, 0);
  }
  f32x16 di;
  di[0] = -m0.x; di[1] = -m0.y; di[2] = -m0.z; di[3] = -m0.w;
  di[4] = -m1.x; di[5] = -m1.y; di[6] = -m1.z; di[7] = -m1.w;
  di[8] = -m2.x; di[9] = -m2.y; di[10] = -m2.z; di[11] = -m2.w;
  di[12] = -m3.x; di[13] = -m3.y; di[14] = -m3.z; di[15] = -m3.w;
  f32x16 d0 = di, d1 = di, d2 = di, d3 = di;
  // own slab slice staged last comp must be resident before ds_read
  if (LAST) asm volatile("s_waitcnt vmcnt(0)" ::: "memory");
  else      asm volatile("s_waitcnt vmcnt(8)" ::: "memory");
  __builtin_amdgcn_sched_barrier(0);
#pragma unroll
  for (int s = 0; s < 8; ++s) {
    const short8 a = *(const short8*)(abuf + RB + (wid * 8 + s) * 1024 + lane * 16);
    d0 = __builtin_amdgcn_mfma_f32_32x32x16_bf16(a, xf[0][s], d0, 0, 0, 0);
    d1 = __builtin_amdgcn_mfma_f32_32x32x16_bf16(a, xf[1][s], d1, 0, 0, 0);
    d2 = __builtin_amdgcn_mfma_f32_32x32x16_bf16(a, xf[2][s], d2, 0, 0, 0);
    d3 = __builtin_amdgcn_mfma_f32_32x32x16_bf16(a, xf[3][s], d3, 0, 0, 0);
  }
  float s0 = 0.f, s1 = 0.f, s2 = 0.f, s3 = 0.f;
#pragma unroll
  for (int i = 0; i < 16; ++i) {
    s0 = fmaf(d0[i], d0[i], s0);
    s1 = fmaf(d1[i], d1[i], s1);
    s2 = fmaf(d2[i], d2[i], s2);
    s3 = fmaf(d3[i], d3[i], s3);
  }
  s0 += __shfl_xor(s0, 32, 64);
  s1 += __shfl_xor(s1, 32, 64);
  s2 += __shfl_xor(s2, 32, 64);
  s3 += __shfl_xor(s3, 32, 64);
  if (half == 0) {
    red[ln][wid] = s0;
    red[32 + ln][wid] = s1;
    red[64 + ln][wid] = s2;
    red[96 + ln][wid] = s3;
  }
  __syncthreads();
  if (tid < 128) {
    float4 r = *(const float4*)red[tid];
    float tot = (r.x + r.y) + (r.z + r.w);
    float v = ck[k] - 0.5f * tot;
    float nm = fmaxf(m, v);
    ssum = ssum * __expf(m - nm) + __expf(v - nm);
    m = nm;
  }
  __syncthreads();
}

__global__ __launch_bounds__(256, 2) void gmm_main(const float* __restrict__ x,
                                                   const unsigned char* __restrict__ Aimg,
                                                   const float* __restrict__ mp2,
                                                   const float* __restrict__ ck2,
                                                   float* __restrict__ out) {
  __shared__ __align__(16) unsigned char abuf[2 * SLABB];
  __shared__ __align__(16) float red[128][4];
  __shared__ float ck[KC];
  const int tid = threadIdx.x;
  const int wid = tid >> 6;  // = gt this wave owns
  const int lane = tid & 63;
  const int half = lane >> 5;
  const int ln = lane & 31;
  const int nbase = blockIdx.x * 128;

  if (tid < KC) ck[tid] = ck2[tid];

  // stage comp 0 -> buf0 (own quarter)
  {
    const unsigned char* gs = Aimg + wid * 8192 + lane * 16;
    unsigned char* ls = abuf + wid * 8192;
#pragma unroll
    for (int i = 0; i < 8; ++i)
      __builtin_amdgcn_global_load_lds(
          (const __attribute__((address_space(1))) void*)(gs + i * 1024),
          (__attribute__((address_space(3))) void*)(ls + i * 1024), 16, 0, 0);
  }

  // B fragments: 4 n-tiles (128 rows) resident in registers for the whole kernel.
  // xf[t][s][j] = x[nbase + t*32 + ln][16s + 8*half + j]
  short8 xf[4][8];
#pragma unroll
  for (int t = 0; t < 4; ++t) {
    const float* xr = x + (size_t)(nbase + t * 32 + ln) * FD + 8 * half;
#pragma unroll
    for (int s = 0; s < 8; ++s) {
      const float4 a = *(const float4*)(xr + 16 * s);
      const float4 b = *(const float4*)(xr + 16 * s + 4);
      short8 f;
      f[0] = (short)f2bf(a.x); f[1] = (short)f2bf(a.y);
      f[2] = (short)f2bf(a.z); f[3] = (short)f2bf(a.w);
      f[4] = (short)f2bf(b.x); f[5] = (short)f2bf(b.y);
      f[6] = (short)f2bf(b.z); f[7] = (short)f2bf(b.w);
      xf[t][s] = f;
    }
  }

  float m = -__builtin_inff(), ssum = 0.f;
  for (int kk = 0; kk < KC - 2; kk += 2) {
    comp_body<0, SLABB, false>(kk, Aimg, mp2, abuf, red, ck, tid, wid, lane, half, ln, xf, m, ssum);
    comp_body<SLABB, 0, false>(kk + 1, Aimg, mp2, abuf, red, ck, tid, wid, lane, half, ln, xf, m, ssum);
  }
  comp_body<0, SLABB, false>(KC - 2, Aimg, mp2, abuf, red, ck, tid, wid, lane, half, ln, xf, m, ssum);
  comp_body<SLABB, 0, true>(KC - 1, Aimg, mp2, abuf, red, ck, tid, wid, lane, half, ln, xf, m, ssum);

  if (tid < 128) out[nbase + tid] = m + logf(ssum);
}

extern "C" void kernel_launch(void* const* d_in, const int* in_sizes, int n_in,
                              void* d_out, int out_size, void* d_ws, size_t ws_size,
                              hipStream_t stream) {
  const float* x = (const float*)d_in[0];
  const float* means = (const float*)d_in[1];
  const float* P = (const float*)d_in[2];
  const float* w = (const float*)d_in[3];
  float* out = (float*)d_out;

  unsigned char* ws = (unsigned char*)d_ws;
  unsigned char* Aimg = ws;                      // 32 * 32768 = 1048576 B
  float* mp2 = (float*)(ws + 1048576);           // 16384 B
  float* ck2 = (float*)(ws + 1048576 + 16384);   // 128 B

  prep_mproj<<<32, 128, 0, stream>>>(means, P, w, mp2, ck2);
  prep_A<<<256, 256, 0, stream>>>(P, Aimg);
  gmm_main<<<NPTS / 128, 256, 0, stream>>>(x, Aimg, mp2, ck2, out);
}

// Round 3
// 89.690 us; speedup vs baseline: 1.0226x; 1.0226x over previous
//
#include <hip/hip_runtime.h>
#include <hip/hip_bf16.h>

// GMM log-likelihood, N=65536, K=32, F=128.
// g-split: wave wid owns g-tile gt=wid (32 rows of P^T); holds B (x) frags for
// 4 n-tiles in registers; each A frag read feeds 4 MFMAs. -mu@P folded into the
// MFMA C-init, with mp prefetched one comp ahead into registers. One barrier
// per comp via double-buffered red[]. Counted vmcnt keeps 12 loads in flight.

#define NPTS 65536
#define KC 32
#define FD 128
#define SLABB 32768  // 4 gt * 8 s * 64 lanes * 16 B

typedef __attribute__((ext_vector_type(8))) short short8;
typedef __attribute__((ext_vector_type(8))) unsigned short ushort8;
typedef __attribute__((ext_vector_type(16))) float f32x16;

static __device__ __forceinline__ unsigned short f2bf(float f) {
  unsigned int u = __float_as_uint(f);
  u += 0x7FFFu + ((u >> 16) & 1u);  // RNE
  return (unsigned short)(u >> 16);
}

// --- prep 1: mp2 (permuted mu@P projections) + ck2 ---
// mp2[((k*4+gt)*2+half)*16 + i] = sum_f means[k][f]*P[k][f][g],
//   g = gt*32 + 4*half + (i&3) + 8*(i>>2)   (32x32 MFMA C-row layout)
__global__ void prep_mproj(const float* __restrict__ means, const float* __restrict__ P,
                           const float* __restrict__ w, float* __restrict__ mp2,
                           float* __restrict__ ck2) {
  int k = blockIdx.x, g = threadIdx.x;  // 32 x 128
  const float* Pk = P + k * FD * FD;
  float acc = 0.f;
  for (int f = 0; f < FD; ++f) acc = fmaf(means[k * FD + f], Pk[f * FD + g], acc);
  int gt = g >> 5, r = g & 31;
  int half = (r >> 2) & 1;
  int i = (r & 3) | ((r >> 3) << 2);
  mp2[((k * 4 + gt) * 2 + half) * 16 + i] = acc;
  __shared__ float red[FD];
  red[g] = logf(Pk[g * FD + g]);
  __syncthreads();
  for (int off = 64; off; off >>= 1) {
    if (g < off) red[g] += red[g + off];
    __syncthreads();
  }
  if (g == 0) ck2[k] = logf(w[k]) + red[0] - 0.5f * (float)FD * 1.8378770664093453f;
}

// --- prep 2: frag-major bf16 A image. chunk id -> (k,gt,s,lane).
// lane l supplies row g=gt*32+(l&31), elements f = 16s + 8*(l>>5) + j.
__global__ void prep_A(const float* __restrict__ P, unsigned char* __restrict__ Aimg) {
  int id = blockIdx.x * 256 + threadIdx.x;  // 0..65535
  int l = id & 63;
  int s = (id >> 6) & 7;
  int gt = (id >> 9) & 3;
  int k = id >> 11;
  int g = gt * 32 + (l & 31);
  int f0 = 16 * s + 8 * (l >> 5);
  ushort8 v;
#pragma unroll
  for (int j = 0; j < 8; ++j) v[j] = f2bf(P[k * 16384 + (f0 + j) * 128 + g]);
  *(ushort8*)(Aimg + (size_t)id * 16) = v;
}

// --- main ---
template <int RB, int WB, int PH, bool LAST>
__device__ __forceinline__ void comp_body(int k, const unsigned char* __restrict__ Aimg,
                                          const float* __restrict__ mp2,
                                          unsigned char* abuf, float (&red)[2][128][4],
                                          const float* ck, int tid, int wid, int lane,
                                          int half, int ln, const short8 (&xf)[4][8],
                                          const float4 (&mpc)[4], float4 (&mpn)[4],
                                          float& m, float& ssum) {
  if (!LAST) {
    // stage S_{k+1} (own quarter, linear both sides), then prefetch M_{k+1}
    const unsigned char* gs = Aimg + (size_t)(k + 1) * SLABB + wid * 8192 + lane * 16;
    unsigned char* ls = abuf + WB + wid * 8192;
#pragma unroll
    for (int i = 0; i < 8; ++i)
      __builtin_amdgcn_global_load_lds(
          (const __attribute__((address_space(1))) void*)(gs + i * 1024),
          (__attribute__((address_space(3))) void*)(ls + i * 1024), 16, 0, 0);
    const float4* mpp = (const float4*)(mp2 + ((size_t)((k + 1) * 4 + wid) * 2 + half) * 16);
    mpn[0] = mpp[0]; mpn[1] = mpp[1]; mpn[2] = mpp[2]; mpn[3] = mpp[3];
  }
  // d-init from mp prefetched LAST comp (no memory wait on critical path)
  f32x16 di;
  di[0] = -mpc[0].x; di[1] = -mpc[0].y; di[2] = -mpc[0].z; di[3] = -mpc[0].w;
  di[4] = -mpc[1].x; di[5] = -mpc[1].y; di[6] = -mpc[1].z; di[7] = -mpc[1].w;
  di[8] = -mpc[2].x; di[9] = -mpc[2].y; di[10] = -mpc[2].z; di[11] = -mpc[2].w;
  di[12] = -mpc[3].x; di[13] = -mpc[3].y; di[14] = -mpc[3].z; di[15] = -mpc[3].w;
  f32x16 d0 = di, d1 = di, d2 = di, d3 = di;
  // prev comp's 8 stage loads must be resident; leave this comp's 12 in flight
  if (LAST) asm volatile("s_waitcnt vmcnt(0)" ::: "memory");
  else      asm volatile("s_waitcnt vmcnt(12)" ::: "memory");
  __builtin_amdgcn_s_setprio(1);
#pragma unroll
  for (int s = 0; s < 8; ++s) {
    const short8 a = *(const short8*)(abuf + RB + (wid * 8 + s) * 1024 + lane * 16);
    d0 = __builtin_amdgcn_mfma_f32_32x32x16_bf16(a, xf[0][s], d0, 0, 0, 0);
    d1 = __builtin_amdgcn_mfma_f32_32x32x16_bf16(a, xf[1][s], d1, 0, 0, 0);
    d2 = __builtin_amdgcn_mfma_f32_32x32x16_bf16(a, xf[2][s], d2, 0, 0, 0);
    d3 = __builtin_amdgcn_mfma_f32_32x32x16_bf16(a, xf[3][s], d3, 0, 0, 0);
  }
  __builtin_amdgcn_s_setprio(0);
  float s0 = 0.f, s1 = 0.f, s2 = 0.f, s3 = 0.f;
#pragma unroll
  for (int i = 0; i < 16; ++i) {
    s0 = fmaf(d0[i], d0[i], s0);
    s1 = fmaf(d1[i], d1[i], s1);
    s2 = fmaf(d2[i], d2[i], s2);
    s3 = fmaf(d3[i], d3[i], s3);
  }
  s0 += __shfl_xor(s0, 32, 64);
  s1 += __shfl_xor(s1, 32, 64);
  s2 += __shfl_xor(s2, 32, 64);
  s3 += __shfl_xor(s3, 32, 64);
  if (half == 0) {
    red[PH][ln][wid] = s0;
    red[PH][32 + ln][wid] = s1;
    red[PH][64 + ln][wid] = s2;
    red[PH][96 + ln][wid] = s3;
  }
  __syncthreads();
  if (tid < 128) {
    float4 r = *(const float4*)red[PH][tid];
    float tot = (r.x + r.y) + (r.z + r.w);
    float v = ck[k] - 0.5f * tot;
    float nm = fmaxf(m, v);
    ssum = ssum * __expf(m - nm) + __expf(v - nm);
    m = nm;
  }
  // no trailing barrier: next comp writes red[PH^1]; red[PH] is reused only
  // two comps later, fenced by the intervening __syncthreads.
}

__global__ __launch_bounds__(256, 2) void gmm_main(const float* __restrict__ x,
                                                   const unsigned char* __restrict__ Aimg,
                                                   const float* __restrict__ mp2,
                                                   const float* __restrict__ ck2,
                                                   float* __restrict__ out) {
  __shared__ __align__(16) unsigned char abuf[2 * SLABB];
  __shared__ __align__(16) float red[2][128][4];
  __shared__ float ck[KC];
  const int tid = threadIdx.x;
  const int wid = tid >> 6;  // = g-tile this wave owns
  const int lane = tid & 63;
  const int half = lane >> 5;
  const int ln = lane & 31;
  const int nbase = blockIdx.x * 128;

  if (tid < KC) ck[tid] = ck2[tid];

  // stage comp 0 -> buf0 (own quarter)
  {
    const unsigned char* gs = Aimg + wid * 8192 + lane * 16;
    unsigned char* ls = abuf + wid * 8192;
#pragma unroll
    for (int i = 0; i < 8; ++i)
      __builtin_amdgcn_global_load_lds(
          (const __attribute__((address_space(1))) void*)(gs + i * 1024),
          (__attribute__((address_space(3))) void*)(ls + i * 1024), 16, 0, 0);
  }
  // M_0
  float4 mpA[4], mpB[4];
  {
    const float4* mpp = (const float4*)(mp2 + ((size_t)(0 * 4 + wid) * 2 + half) * 16);
    mpA[0] = mpp[0]; mpA[1] = mpp[1]; mpA[2] = mpp[2]; mpA[3] = mpp[3];
  }

  // B fragments: 4 n-tiles (128 rows) resident in registers for the whole kernel.
  // xf[t][s][j] = x[nbase + t*32 + ln][16s + 8*half + j]
  short8 xf[4][8];
#pragma unroll
  for (int t = 0; t < 4; ++t) {
    const float* xr = x + (size_t)(nbase + t * 32 + ln) * FD + 8 * half;
#pragma unroll
    for (int s = 0; s < 8; ++s) {
      const float4 a = *(const float4*)(xr + 16 * s);
      const float4 b = *(const float4*)(xr + 16 * s + 4);
      short8 f;
      f[0] = (short)f2bf(a.x); f[1] = (short)f2bf(a.y);
      f[2] = (short)f2bf(a.z); f[3] = (short)f2bf(a.w);
      f[4] = (short)f2bf(b.x); f[5] = (short)f2bf(b.y);
      f[6] = (short)f2bf(b.z); f[7] = (short)f2bf(b.w);
      xf[t][s] = f;
    }
  }

  float m = -__builtin_inff(), ssum = 0.f;
  for (int kk = 0; kk < KC - 2; kk += 2) {
    comp_body<0, SLABB, 0, false>(kk, Aimg, mp2, abuf, red, ck, tid, wid, lane, half,
                                  ln, xf, mpA, mpB, m, ssum);
    comp_body<SLABB, 0, 1, false>(kk + 1, Aimg, mp2, abuf, red, ck, tid, wid, lane,
                                  half, ln, xf, mpB, mpA, m, ssum);
  }
  comp_body<0, SLABB, 0, false>(KC - 2, Aimg, mp2, abuf, red, ck, tid, wid, lane, half,
                                ln, xf, mpA, mpB, m, ssum);
  comp_body<SLABB, 0, 1, true>(KC - 1, Aimg, mp2, abuf, red, ck, tid, wid, lane, half,
                               ln, xf, mpB, mpA, m, ssum);

  if (tid < 128) out[nbase + tid] = m + logf(ssum);
}

extern "C" void kernel_launch(void* const* d_in, const int* in_sizes, int n_in,
                              void* d_out, int out_size, void* d_ws, size_t ws_size,
                              hipStream_t stream) {
  const float* x = (const float*)d_in[0];
  const float* means = (const float*)d_in[1];
  const float* P = (const float*)d_in[2];
  const float* w = (const float*)d_in[3];
  float* out = (float*)d_out;

  unsigned char* ws = (unsigned char*)d_ws;
  unsigned char* Aimg = ws;                      // 32 * 32768 = 1048576 B
  float* mp2 = (float*)(ws + 1048576);           // 16384 B
  float* ck2 = (float*)(ws + 1048576 + 16384);   // 128 B

  prep_mproj<<<32, 128, 0, stream>>>(means, P, w, mp2, ck2);
  prep_A<<<256, 256, 0, stream>>>(P, Aimg);
  gmm_main<<<NPTS / 128, 256, 0, stream>>>(x, Aimg, mp2, ck2, out);
}